// Round 2
// baseline (62302.454 us; speedup 1.0000x reference)
//
#include <hip/hip_runtime.h>
#include <cmath>

#define BB 64      // batch
#define TT 512     // seq len
#define HH 512     // hidden
#define GG 2048    // 4*H
#define TCH 64     // time chunk
#define LDT 132    // LDS tile row stride (floats), quad-aligned

// ---------------------------------------------------------------------------
// xg GEMM: XG[tl][gc][b] = sum_k Wih[gc][k]*x[(b,t)][k] + bih[gc]+bhh[gc]
// A-operand = W_ih rows (gc,k); B-operand = x rows m=(tl*64+b).
// GATHER=true: x row = emb[tok[b][t]]; else x = Y in [T][H][B] layout.
// 128x128 tile, TK=32, 256 threads, 8x8 acc/thread, swizzled LDS.
// ---------------------------------------------------------------------------
template<bool GATHER>
__global__ __launch_bounds__(256) void xg_gemm(
    const float* __restrict__ Xsrc, const int* __restrict__ tok,
    const float* __restrict__ Wih, const float* __restrict__ bih,
    const float* __restrict__ bhh, float* __restrict__ XG, int t0)
{
  __shared__ float As[32 * LDT];
  __shared__ float Bs[32 * LDT];
  const int tid = threadIdx.x;
  const int tc = tid & 15, tr = tid >> 4;
  const int m0 = blockIdx.x * 128;   // m = tl*64 + b (chunk-local)
  const int g0 = blockIdx.y * 128;   // gate-col tile

  float acc[8][8];
#pragma unroll
  for (int i = 0; i < 8; ++i)
#pragma unroll
    for (int j = 0; j < 8; ++j) acc[i][j] = 0.f;

  float4 ra[4], rb[4];
  // initial loads (k0 = 0)
#pragma unroll
  for (int i = 0; i < 4; ++i) {
    const int f = tid + i * 256;
    ra[i] = *(const float4*)&Wih[(size_t)(g0 + (f >> 3)) * HH + ((f & 7) << 2)];
  }
#pragma unroll
  for (int i = 0; i < 4; ++i) {
    const int f = tid + i * 256;
    if (GATHER) {
      const int m = m0 + (f >> 3);
      const int tok_i = tok[(m & 63) * TT + t0 + (m >> 6)];
      rb[i] = *(const float4*)&Xsrc[(size_t)tok_i * HH + ((f & 7) << 2)];
    } else {
      rb[i] = *(const float4*)&Xsrc[((size_t)(t0 + (m0 >> 6) + (f >> 9)) * HH
                                     + ((f >> 4) & 31)) * BB + ((f & 15) << 2)];
    }
  }

  for (int kt = 0; kt < 16; ++kt) {
    // ---- store staged registers to LDS (transpose+swizzle for row-major srcs)
#pragma unroll
    for (int i = 0; i < 4; ++i) {
      const int f = tid + i * 256;
      const int row = f >> 3, c4 = f & 7, s = c4 & 3;
      const int col = (((row >> 2) ^ s) << 2) + (row & 3);
      As[(c4 * 4 + 0) * LDT + col] = ra[i].x;
      As[(c4 * 4 + 1) * LDT + col] = ra[i].y;
      As[(c4 * 4 + 2) * LDT + col] = ra[i].z;
      As[(c4 * 4 + 3) * LDT + col] = ra[i].w;
    }
#pragma unroll
    for (int i = 0; i < 4; ++i) {
      const int f = tid + i * 256;
      if (GATHER) {
        const int row = f >> 3, c4 = f & 7, s = c4 & 3;
        const int col = (((row >> 2) ^ s) << 2) + (row & 3);
        Bs[(c4 * 4 + 0) * LDT + col] = rb[i].x;
        Bs[(c4 * 4 + 1) * LDT + col] = rb[i].y;
        Bs[(c4 * 4 + 2) * LDT + col] = rb[i].z;
        Bs[(c4 * 4 + 3) * LDT + col] = rb[i].w;
      } else {
        const int kk = (f >> 4) & 31, s = (kk >> 2) & 3;
        const int mq = (((f >> 9) << 4) + (f & 15)) ^ s;
        *(float4*)&Bs[kk * LDT + (mq << 2)] = rb[i];
      }
    }
    __syncthreads();
    // ---- prefetch next tile into registers
    if (kt < 15) {
      const int k0 = (kt + 1) * 32;
#pragma unroll
      for (int i = 0; i < 4; ++i) {
        const int f = tid + i * 256;
        ra[i] = *(const float4*)&Wih[(size_t)(g0 + (f >> 3)) * HH + k0 + ((f & 7) << 2)];
      }
#pragma unroll
      for (int i = 0; i < 4; ++i) {
        const int f = tid + i * 256;
        if (GATHER) {
          const int m = m0 + (f >> 3);
          const int tok_i = tok[(m & 63) * TT + t0 + (m >> 6)];
          rb[i] = *(const float4*)&Xsrc[(size_t)tok_i * HH + k0 + ((f & 7) << 2)];
        } else {
          rb[i] = *(const float4*)&Xsrc[((size_t)(t0 + (m0 >> 6) + (f >> 9)) * HH
                                         + k0 + ((f >> 4) & 31)) * BB + ((f & 15) << 2)];
        }
      }
    }
    // ---- compute on LDS tile
#pragma unroll
    for (int k = 0; k < 32; ++k) {
      const int s = (k >> 2) & 3;
      const float4 a0 = *(const float4*)&As[k * LDT + ((tr ^ s) << 2)];
      const float4 a1 = *(const float4*)&As[k * LDT + ((16 + (tr ^ s)) << 2)];
      const float4 b0 = *(const float4*)&Bs[k * LDT + ((tc ^ s) << 2)];
      const float4 b1 = *(const float4*)&Bs[k * LDT + ((16 + (tc ^ s)) << 2)];
      const float av[8] = {a0.x, a0.y, a0.z, a0.w, a1.x, a1.y, a1.z, a1.w};
      const float bv[8] = {b0.x, b0.y, b0.z, b0.w, b1.x, b1.y, b1.z, b1.w};
#pragma unroll
      for (int i2 = 0; i2 < 8; ++i2)
#pragma unroll
        for (int j2 = 0; j2 < 8; ++j2)
          acc[i2][j2] = fmaf(av[i2], bv[j2], acc[i2][j2]);
    }
    __syncthreads();
  }

  // ---- epilogue: add bias, write XG[tl][gc][b] (coalesced over b)
#pragma unroll
  for (int ah = 0; ah < 2; ++ah)
#pragma unroll
    for (int i = 0; i < 4; ++i) {
      const int gc = g0 + ah * 64 + tr * 4 + i;
      const float bias = bih[gc] + bhh[gc];
#pragma unroll
      for (int bh = 0; bh < 2; ++bh) {
        const int tl_ = (m0 >> 6) + bh;
        float4 v;
        v.x = acc[ah * 4 + i][bh * 4 + 0] + bias;
        v.y = acc[ah * 4 + i][bh * 4 + 1] + bias;
        v.z = acc[ah * 4 + i][bh * 4 + 2] + bias;
        v.w = acc[ah * 4 + i][bh * 4 + 3] + bias;
        *(float4*)&XG[((size_t)tl_ * GG + gc) * BB + (tc << 2)] = v;
      }
    }
}

// ---------------------------------------------------------------------------
// One LSTM timestep. 256 WGs; WG g owns h-cols {2g, 2g+1} -> 8 gate cols.
// Waves b-tiled (16 batch rows each); h chunk + W slice staged in LDS.
// h ping-pong: read h_in (t-1 state), write h_out (t state) -- no intra-grid
// read/write race. c is per-WG-column owned, single buffer is safe.
// ---------------------------------------------------------------------------
__global__ __launch_bounds__(256) void lstm_step(
    const float* __restrict__ XG, const float* __restrict__ Whh,
    const float* __restrict__ h_in, float* __restrict__ h_out,
    float* __restrict__ c, float* __restrict__ Y,
    int t, int tl, int first)
{
  __shared__ float hs[64 * LDT];
  __shared__ float ws2[8 * LDT];
  __shared__ float gs[512];
  const int tid = threadIdx.x;
  const int g = blockIdx.x;
  const int w = tid >> 6, lane = tid & 63;
  const int bl = lane >> 2, gl = lane & 3;
  const int b = w * 16 + bl;
  float acc0 = 0.f, acc1 = 0.f;

  if (!first) {
    for (int kc = 0; kc < HH; kc += 128) {
      // stage h chunk [64][128] (h_in is [B][H]: direct copy, no transpose)
#pragma unroll
      for (int i = 0; i < 8; ++i) {
        const int f = tid + i * 256;
        const int hb = f >> 5, k4 = f & 31;
        const float4 v = *(const float4*)&h_in[(size_t)hb * HH + kc + (k4 << 2)];
        *(float4*)&hs[hb * LDT + (k4 << 2)] = v;
      }
      { // stage 8 W rows (wrow = j*4 + q)
        const int wrow = tid >> 5, k4 = tid & 31;
        const int q = wrow & 3, j = wrow >> 2;
        const int gc = q * HH + 2 * g + j;
        const float4 v = *(const float4*)&Whh[(size_t)gc * HH + kc + (k4 << 2)];
        *(float4*)&ws2[wrow * LDT + (k4 << 2)] = v;
      }
      __syncthreads();
#pragma unroll
      for (int k4 = 0; k4 < 32; ++k4) {
        const float4 hv = *(const float4*)&hs[b * LDT + (k4 << 2)];
        const float4 w0 = *(const float4*)&ws2[gl * LDT + (k4 << 2)];
        const float4 w1 = *(const float4*)&ws2[(4 + gl) * LDT + (k4 << 2)];
        acc0 = fmaf(hv.x, w0.x, acc0); acc0 = fmaf(hv.y, w0.y, acc0);
        acc0 = fmaf(hv.z, w0.z, acc0); acc0 = fmaf(hv.w, w0.w, acc0);
        acc1 = fmaf(hv.x, w1.x, acc1); acc1 = fmaf(hv.y, w1.y, acc1);
        acc1 = fmaf(hv.z, w1.z, acc1); acc1 = fmaf(hv.w, w1.w, acc1);
      }
      __syncthreads();
    }
  }

  { // add xg, exchange gates through LDS
    const int gc0 = gl * HH + 2 * g;
    acc0 += XG[((size_t)tl * GG + gc0) * BB + b];
    acc1 += XG[((size_t)tl * GG + gc0 + 1) * BB + b];
    gs[gl * 128 + (b << 1)] = acc0;
    gs[gl * 128 + (b << 1) + 1] = acc1;
  }
  __syncthreads();
  if (tid < 128) {
    const int bb = tid & 63, j = tid >> 6;
    const float iv = gs[0 * 128 + (bb << 1) + j];
    const float fv = gs[1 * 128 + (bb << 1) + j];
    const float gv = gs[2 * 128 + (bb << 1) + j];
    const float ov = gs[3 * 128 + (bb << 1) + j];
    const int hc = 2 * g + j;
    const float cold = first ? 0.f : c[hc * BB + bb];
    const float si = 1.f / (1.f + expf(-iv));
    const float sf = 1.f / (1.f + expf(-fv));
    const float so = 1.f / (1.f + expf(-ov));
    const float cn = sf * cold + si * tanhf(gv);
    const float hn = so * tanhf(cn);
    c[hc * BB + bb] = cn;
    h_out[(size_t)bb * HH + hc] = hn;
    Y[((size_t)t * HH + hc) * BB + bb] = hn;
  }
}

// ---------------------------------------------------------------------------
// Classifier: out[b][n] = feature(b) . Wcls[n] + bcls[n], feature = Y[511][:][b]
// ---------------------------------------------------------------------------
__global__ __launch_bounds__(64) void cls_kernel(
    const float* __restrict__ Y, const float* __restrict__ Wcls,
    const float* __restrict__ bcls, float* __restrict__ out)
{
  __shared__ float feat[512];
  const int b = blockIdx.x, tid = threadIdx.x;
  for (int k = tid; k < HH; k += 64)
    feat[k] = Y[((size_t)(TT - 1) * HH + k) * BB + b];
  __syncthreads();
  if (tid < 20) {
    float acc = bcls[tid];
    for (int k = 0; k < HH; ++k) acc = fmaf(feat[k], Wcls[tid * HH + k], acc);
    out[b * 20 + tid] = acc;
  }
}

// ---------------------------------------------------------------------------
extern "C" void kernel_launch(void* const* d_in, const int* in_sizes, int n_in,
                              void* d_out, int out_size, void* d_ws, size_t ws_size,
                              hipStream_t stream) {
  (void)in_sizes; (void)n_in; (void)out_size; (void)ws_size;
  const int*   tok  = (const int*)d_in[0];
  const float* emb  = (const float*)d_in[1];
  const float* Wih  = (const float*)d_in[2];
  const float* Whh  = (const float*)d_in[3];
  const float* bih  = (const float*)d_in[4];
  const float* bhh  = (const float*)d_in[5];
  const float* Wcls = (const float*)d_in[6];
  const float* bcls = (const float*)d_in[7];
  float* out = (float*)d_out;

  // ws layout: Y [T][H][B] (64MB) | XG [TCH][G4][B] (32MB) | h0 | h1 | c
  float* Y  = (float*)d_ws;
  float* XG = Y + (size_t)TT * HH * BB;
  float* h0 = XG + (size_t)TCH * GG * BB;
  float* h1 = h0 + (size_t)BB * HH;
  float* c  = h1 + (size_t)BB * HH;

  for (int l = 0; l < 5; ++l) {
    const float* wih_l = Wih + (size_t)l * GG * HH;
    const float* whh_l = Whh + (size_t)l * GG * HH;
    const float* bih_l = bih + (size_t)l * GG;
    const float* bhh_l = bhh + (size_t)l * GG;
    for (int t0 = 0; t0 < TT; t0 += TCH) {
      if (l == 0)
        xg_gemm<true><<<dim3(32, 16), 256, 0, stream>>>(emb, tok, wih_l, bih_l, bhh_l, XG, t0);
      else
        xg_gemm<false><<<dim3(32, 16), 256, 0, stream>>>(Y, nullptr, wih_l, bih_l, bhh_l, XG, t0);
      for (int tl = 0; tl < TCH; ++tl) {
        const int t = t0 + tl;
        const float* h_in  = (t & 1) ? h1 : h0;
        float*       h_out = (t & 1) ? h0 : h1;
        lstm_step<<<256, 256, 0, stream>>>(XG, whh_l, h_in, h_out, c, Y, t, tl, (t == 0) ? 1 : 0);
      }
    }
  }
  cls_kernel<<<64, 64, 0, stream>>>(Y, Wcls, bcls, out);
}